// Round 10
// baseline (199.821 us; speedup 1.0000x reference)
//
#include <hip/hip_runtime.h>
#include <math.h>

#define NSIG 1000
#define NP   3997      // interp points = FFT length (odd)
#define KHALF 1999     // distinct spectrum bins: k = 0..1998 (rest mirror)
#define NW   995       // n_windows
#define WIN  20
#define STEPW 4
#define BATCH 4
#define NCH  125       // window chunks per batch row (8 windows each)
#define CW   8         // windows per chunk
#define NBLK2 (NCH * BATCH)   // 500 blocks in fused kernel (co-resident by launch_bounds)

// ws layout (bytes):
//   ks   : [0, 65536)        BATCH*NP floats; pad is read-only garbage
//   tw   : [65536, 97512)    NP float2
//   S    : [98304, 226208)   BATCH*NP float2 (first KHALF per row used)
//   rmax : [226304, 226320)  BATCH uint
//   bar  : [226320, 226324)  uint barrier counter (zeroed each call by K1)
//   cmax : [226432, 228432)  BATCH*NCH floats
//   wcut : [229376, 245296)  BATCH*NW floats

__device__ __forceinline__ double interp_at(const float* __restrict__ s, int p) {
    int i0 = p >> 2;
    int si = p & 3;
    double ss = 0.25 * (double)si;
    const double A = -0.75;
    double d0 = ss + 1.0;
    double w0 = ((A * d0 - 5.0 * A) * d0 + 8.0 * A) * d0 - 4.0 * A;
    double w1 = ((A + 2.0) * ss - (A + 3.0)) * ss * ss + 1.0;
    double d2 = 1.0 - ss;
    double w2 = ((A + 2.0) * d2 - (A + 3.0)) * d2 * d2 + 1.0;
    double d3 = 2.0 - ss;
    double w3 = ((A * d3 - 5.0 * A) * d3 + 8.0 * A) * d3 - 4.0 * A;
    int im1 = i0 - 1; if (im1 < 0) im1 = 0;
    int ip1 = i0 + 1; if (ip1 > NSIG - 1) ip1 = NSIG - 1;
    int ip2 = i0 + 2; if (ip2 > NSIG - 1) ip2 = NSIG - 1;
    return w0 * (double)s[im1] + w1 * (double)s[i0] +
           w2 * (double)s[ip1] + w3 * (double)s[ip2];
}

// K1: fused init + full DFT (unchanged from R9) + zero barrier counter.
__global__ __launch_bounds__(512) void dft_init_kernel(
        const float* __restrict__ sig, const float* __restrict__ gamma_raw,
        float* __restrict__ ks, float2* __restrict__ tw, float2* __restrict__ S,
        unsigned int* __restrict__ rmax, unsigned int* __restrict__ bar) {
    __shared__ float   lks[NP];
    __shared__ double2 redd[512];
    int b = blockIdx.y;
    int bx = blockIdx.x;
    int tid = threadIdx.x;
    const float* srow = sig + b * NSIG;

    double lmin = 1e300;
    #pragma unroll
    for (int i = 0; i < 8; ++i) {
        int p = tid + i * 512;
        if (p < NP) lmin = fmin(lmin, interp_at(srow, p));
    }
    redd[tid].x = lmin;
    __syncthreads();
    for (int s = 256; s > 0; s >>= 1) {
        if (tid < s) redd[tid].x = fmin(redd[tid].x, redd[tid + s].x);
        __syncthreads();
    }
    double m = fmin(redd[0].x, 0.0);
    double g0r = (double)gamma_raw[0], g1r = (double)gamma_raw[1];
    double mx = fmax(g0r, g1r);
    double e0 = exp(g0r - mx), e1 = exp(g1r - mx);
    double inv = 1.0 / (e0 + e1);
    double g0 = e0 * inv, g1 = e1 * inv;
    #pragma unroll
    for (int i = 0; i < 8; ++i) {
        int p = tid + i * 512;
        if (p < NP) {
            double x = interp_at(srow, p) - m;
            double poly = (x + 1.3) * (x + 1.3);
            double gauss = exp(-0.5 * (x - 0.7) * (x - 0.7));
            float v = (float)(g0 * poly + g1 * gauss);
            lks[p] = v;
            if (bx == 0) ks[b * NP + p] = v;
        }
    }
    if (b == 0 && bx < 8) {
        int mm = bx * 512 + tid;
        if (mm < NP) {
            double ang = -6.283185307179586476925286766559 * ((double)mm / (double)NP);
            double sv, cv; sincos(ang, &sv, &cv);
            tw[mm] = make_float2((float)cv, (float)sv);
        }
        if (bx == 0 && tid < BATCH) rmax[tid] = 0u;
        if (bx == 0 && tid == 0) *bar = 0u;
    }
    __syncthreads();

    int kk = tid & 15, tc = tid >> 4;
    int k = bx * 16 + kk;
    double sr = 0.0, si = 0.0;
    if (k < KHALF) {
        int t0 = tc * 125;
        int t1 = t0 + 125; if (t1 > NP) t1 = NP;
        const double TWO_PI = 6.283185307179586476925286766559;
        double base = -TWO_PI / (double)NP;
        double rr, ri;
        sincos(base * (double)k, &ri, &rr);
        int m0 = (k * t0) % NP;
        double pr, pi;
        sincos(base * (double)m0, &pi, &pr);
        for (int t = t0; t < t1; ++t) {
            double kv = (double)lks[t];
            sr = fma(kv, pr, sr);
            si = fma(kv, pi, si);
            double nr = pr * rr - pi * ri;
            double ni = pr * ri + pi * rr;
            pr = nr; pi = ni;
        }
    }
    redd[tid] = make_double2(sr, si);
    __syncthreads();
    for (int s = 256; s >= 16; s >>= 1) {
        if (tid < s) {
            redd[tid].x += redd[tid + s].x;
            redd[tid].y += redd[tid + s].y;
        }
        __syncthreads();
    }
    if (tid < 16) {
        int kw = bx * 16 + tid;
        if (kw < KHALF)
            S[b * NP + kw] = make_float2((float)redd[tid].x, (float)redd[tid].y);
    }
}

__device__ __forceinline__ float wavemax(float x) {
    #pragma unroll
    for (int off = 32; off > 0; off >>= 1)
        x = fmaxf(x, __shfl_xor(x, off));
    return x;
}

// sliding step bin n: W += (cn*r20 - co) * q ; q *= r
#define SLIDE1(n, co, cn) { \
    float ax = fmaf((cn), T##n.x, -(co)); \
    float ay = (cn) * T##n.y; \
    Wx##n = fmaf(ax, Q##n.x, fmaf(-ay, Q##n.y, Wx##n)); \
    Wy##n = fmaf(ax, Q##n.y, fmaf(ay, Q##n.x, Wy##n)); \
    float tq = fmaf(Q##n.x, R##n.x, -(Q##n.y * R##n.y)); \
    Q##n.y = fmaf(Q##n.x, R##n.y, Q##n.y * R##n.x); \
    Q##n.x = tq; }

#define SLIDEJ(co, cn) SLIDE1(0, co, cn) SLIDE1(1, co, cn) SLIDE1(2, co, cn) SLIDE1(3, co, cn)

#define SLIDE4(base) { \
    { float co = kp[(base) + 0], cn = kp[(base) + 20]; SLIDEJ(co, cn) } \
    { float co = kp[(base) + 1], cn = kp[(base) + 21]; SLIDEJ(co, cn) } \
    { float co = kp[(base) + 2], cn = kp[(base) + 22]; SLIDEJ(co, cn) } \
    { float co = kp[(base) + 3], cn = kp[(base) + 23]; SLIDEJ(co, cn) } }

#define WINBODY(w) { \
    float M0 = sqrtf(fmaf(Wx0, Wx0, Wy0 * Wy0)); \
    float M1m = sqrtf(fmaf(Wx1, Wx1, Wy1 * Wy1)); \
    float M2m = sqrtf(fmaf(Wx2, Wx2, Wy2 * Wy2)); \
    float M3m = sqrtf(fmaf(Wx3, Wx3, Wy3 * Wy3)); \
    float lm = fmaxf(fmaxf(M0, M1m), fmaxf(M2m, v3 ? M3m : 0.f)); \
    lm = wavemax(lm); \
    if ((tid & 63) == 0) wred[tid >> 6] = lm; \
    __syncthreads(); \
    float bm = fmaxf(fmaxf(fmaxf(wred[0], wred[1]), fmaxf(wred[2], wred[3])), \
                     fmaxf(fmaxf(wred[4], wred[5]), fmaxf(wred[6], wred[7]))); \
    float cut = bm * alpha; \
    __syncthreads(); \
    if (w0 + (w) < NW) { \
        if (tid == 0) wcut[b * NW + w0 + (w)] = cut; \
        float r0v = 0.f, r1v = 0.f, r2v = 0.f, r3v = 0.f; \
        { float dr = Sv0.x - Wx0, di = Sv0.y - Wy0; float m1 = sqrtf(fmaf(dr, dr, di * di)); \
          if (M0 > cut) r0v = fminf(M0, m1 * M0); } \
        { float dr = Sv1.x - Wx1, di = Sv1.y - Wy1; float m1 = sqrtf(fmaf(dr, dr, di * di)); \
          if (M1m > cut) r1v = fminf(M1m, m1 * M1m); } \
        { float dr = Sv2.x - Wx2, di = Sv2.y - Wy2; float m1 = sqrtf(fmaf(dr, dr, di * di)); \
          if (M2m > cut) r2v = fminf(M2m, m1 * M2m); } \
        { float dr = Sv3.x - Wx3, di = Sv3.y - Wy3; float m1 = sqrtf(fmaf(dr, dr, di * di)); \
          if (M3m > cut) r3v = fminf(M3m, m1 * M3m); } \
        rl = fmaxf(rl, fmaxf(fmaxf(r0v, r1v), fmaxf(r2v, r3v))); \
    } }

// finalize survivor bin epilogue
#define FINBIN(n, kn, valid) { \
    if (valid) { \
        float M = sqrtf(fmaf(Dx##n, Dx##n, Dy##n * Dy##n)); \
        float2 P = tw[((kn) * start) % NP]; \
        float Wr = fmaf(P.x, Dx##n, -(P.y * Dy##n)); \
        float Wi = fmaf(P.x, Dy##n, P.y * Dx##n); \
        float2 Sv = Sb[kn]; \
        float dr = Sv.x - Wr, di = Sv.y - Wi; \
        float M1 = sqrtf(fmaf(dr, dr, di * di)); \
        float res = 0.f; \
        if (M > cut) res = fminf(M, M1 * M); \
        float f = (res > thr) ? res : 0.f; \
        out[base + (kn)] = f; \
        if ((kn) > 0) out[base + NP - (kn)] = f; \
    } }

// K2: fused window + global software barrier + finalize.
// Grid = 500 blocks x 512 thr; __launch_bounds__(512,4) caps VGPR at 128 ->
// >=2 blocks/CU -> capacity 512 >= 500 -> all blocks co-resident (no deadlock).
__global__ __launch_bounds__(512, 4) void winfin_kernel(
        const float* __restrict__ ks, const float2* __restrict__ tw,
        const float2* __restrict__ S, const float* __restrict__ alpha_p,
        const float* __restrict__ beta_p, float* __restrict__ wcut,
        float* __restrict__ cmax, unsigned int* __restrict__ rmax,
        unsigned int* __restrict__ bar, float* __restrict__ out) {
    __shared__ float wred[8];
    int bid = blockIdx.x;
    int b = bid & 3;
    int wc = bid >> 2;
    int w0 = wc * CW;
    int s0 = w0 * STEPW;
    int tid = threadIdx.x;
    float alpha = *alpha_p;
    const float* kp = ks + b * NP + s0;   // block-uniform -> s_load taps

    int k0 = tid, k1 = tid + 512, k2 = tid + 1024, k3 = tid + 1536;
    bool v3 = (k3 < KHALF);

    {
        float2 R0 = tw[k0], R1 = tw[k1], R2 = tw[k2], R3 = tw[k3];
        float2 T0 = tw[(20 * k0) % NP], T1 = tw[(20 * k1) % NP],
               T2 = tw[(20 * k2) % NP], T3 = tw[(20 * k3) % NP];
        float2 Q0 = tw[(k0 * s0) % NP], Q1 = tw[(k1 * s0) % NP],
               Q2 = tw[(k2 * s0) % NP], Q3 = tw[(k3 * s0) % NP];
        const float2* Sb = S + b * NP;
        float2 Sv0 = Sb[k0], Sv1 = Sb[k1], Sv2 = Sb[k2], Sv3 = Sb[k3];

        float Dx0 = kp[19], Dy0 = 0.f, Dx1 = kp[19], Dy1 = 0.f,
              Dx2 = kp[19], Dy2 = 0.f, Dx3 = kp[19], Dy3 = 0.f;
        #pragma unroll
        for (int j = 18; j >= 0; --j) {
            float a = kp[j];
            float nx, ny;
            nx = fmaf(Dx0, R0.x, fmaf(-Dy0, R0.y, a));
            ny = fmaf(Dy0, R0.x, Dx0 * R0.y);
            Dx0 = nx; Dy0 = ny;
            nx = fmaf(Dx1, R1.x, fmaf(-Dy1, R1.y, a));
            ny = fmaf(Dy1, R1.x, Dx1 * R1.y);
            Dx1 = nx; Dy1 = ny;
            nx = fmaf(Dx2, R2.x, fmaf(-Dy2, R2.y, a));
            ny = fmaf(Dy2, R2.x, Dx2 * R2.y);
            Dx2 = nx; Dy2 = ny;
            nx = fmaf(Dx3, R3.x, fmaf(-Dy3, R3.y, a));
            ny = fmaf(Dy3, R3.x, Dx3 * R3.y);
            Dx3 = nx; Dy3 = ny;
        }
        float Wx0 = fmaf(Q0.x, Dx0, -(Q0.y * Dy0));
        float Wy0 = fmaf(Q0.x, Dy0, Q0.y * Dx0);
        float Wx1 = fmaf(Q1.x, Dx1, -(Q1.y * Dy1));
        float Wy1 = fmaf(Q1.x, Dy1, Q1.y * Dx1);
        float Wx2 = fmaf(Q2.x, Dx2, -(Q2.y * Dy2));
        float Wy2 = fmaf(Q2.x, Dy2, Q2.y * Dx2);
        float Wx3 = fmaf(Q3.x, Dx3, -(Q3.y * Dy3));
        float Wy3 = fmaf(Q3.x, Dy3, Q3.y * Dx3);

        float rl = 0.f;

        WINBODY(0)
        SLIDE4(0)  WINBODY(1)
        SLIDE4(4)  WINBODY(2)
        SLIDE4(8)  WINBODY(3)
        SLIDE4(12) WINBODY(4)
        SLIDE4(16) WINBODY(5)
        SLIDE4(20) WINBODY(6)
        SLIDE4(24) WINBODY(7)

        rl = wavemax(rl);
        if ((tid & 63) == 0) wred[tid >> 6] = rl;
        __syncthreads();
        if (tid == 0) {
            float bm = fmaxf(fmaxf(fmaxf(wred[0], wred[1]), fmaxf(wred[2], wred[3])),
                             fmaxf(fmaxf(wred[4], wred[5]), fmaxf(wred[6], wred[7])));
            cmax[b * NCH + wc] = bm;
            atomicMax(&rmax[b], __float_as_uint(bm));
        }
    }

    // ---- global software barrier (all 500 blocks co-resident) ----
    __syncthreads();
    __threadfence();
    if (tid == 0) {
        atomicAdd(bar, 1u);
        while (atomicAdd(bar, 0u) < (unsigned)NBLK2)
            __builtin_amdgcn_s_sleep(2);
    }
    __syncthreads();
    __threadfence();

    // ---- finalize: 8 rows per block, grid-stride ----
    float beta = *beta_p;
    for (int i = 0; i < 8; ++i) {
        int rr = bid + i * NBLK2;
        if (rr >= BATCH * NW) break;
        int fb = rr / NW;
        int w = rr - fb * NW;
        float thr = beta * __uint_as_float(rmax[fb]);
        size_t base = (size_t)rr * NP;
        if (cmax[fb * NCH + (w >> 3)] <= thr) {
            // dense zero row, vectorized: head scalars, float4 body, tail
            int h = (4 - (int)(base & 3)) & 3;
            int nv = (NP - h) >> 2;
            int t0 = h + (nv << 2);
            float4* vp = (float4*)(out + base + h);
            float4 z4 = make_float4(0.f, 0.f, 0.f, 0.f);
            for (int v = tid; v < nv; v += 512) vp[v] = z4;
            if (tid < h) out[base + tid] = 0.f;
            if (tid < NP - t0) out[base + t0 + tid] = 0.f;
            continue;
        }
        int start = w * STEPW;
        const float* kpf = ks + fb * NP + start;
        float cut = wcut[fb * NW + w];
        const float2* Sb = S + fb * NP;
        float2 R0 = tw[k0], R1 = tw[k1], R2 = tw[k2], R3 = tw[k3];
        float Dx0 = kpf[19], Dy0 = 0.f, Dx1 = kpf[19], Dy1 = 0.f,
              Dx2 = kpf[19], Dy2 = 0.f, Dx3 = kpf[19], Dy3 = 0.f;
        #pragma unroll
        for (int j = 18; j >= 0; --j) {
            float a = kpf[j];
            float nx, ny;
            nx = fmaf(Dx0, R0.x, fmaf(-Dy0, R0.y, a));
            ny = fmaf(Dy0, R0.x, Dx0 * R0.y);
            Dx0 = nx; Dy0 = ny;
            nx = fmaf(Dx1, R1.x, fmaf(-Dy1, R1.y, a));
            ny = fmaf(Dy1, R1.x, Dx1 * R1.y);
            Dx1 = nx; Dy1 = ny;
            nx = fmaf(Dx2, R2.x, fmaf(-Dy2, R2.y, a));
            ny = fmaf(Dy2, R2.x, Dx2 * R2.y);
            Dx2 = nx; Dy2 = ny;
            nx = fmaf(Dx3, R3.x, fmaf(-Dy3, R3.y, a));
            ny = fmaf(Dy3, R3.x, Dx3 * R3.y);
            Dx3 = nx; Dy3 = ny;
        }
        FINBIN(0, k0, true)
        FINBIN(1, k1, true)
        FINBIN(2, k2, true)
        FINBIN(3, k3, v3)
    }
}

extern "C" void kernel_launch(void* const* d_in, const int* in_sizes, int n_in,
                              void* d_out, int out_size, void* d_ws, size_t ws_size,
                              hipStream_t stream) {
    const float* sig       = (const float*)d_in[0];
    const float* alpha_p   = (const float*)d_in[1];
    const float* beta_p    = (const float*)d_in[2];
    const float* gamma_raw = (const float*)d_in[3];
    char* ws = (char*)d_ws;
    float*        ks   = (float*)(ws + 0);
    float2*       tw   = (float2*)(ws + 65536);
    float2*       S    = (float2*)(ws + 98304);
    unsigned int* rmax = (unsigned int*)(ws + 226304);
    unsigned int* bar  = (unsigned int*)(ws + 226320);
    float*        cmax = (float*)(ws + 226432);
    float*        wcut = (float*)(ws + 229376);
    float* out = (float*)d_out;

    hipLaunchKernelGGL(dft_init_kernel, dim3(125, BATCH), dim3(512), 0, stream,
                       sig, gamma_raw, ks, tw, S, rmax, bar);
    hipLaunchKernelGGL(winfin_kernel,   dim3(NBLK2),      dim3(512), 0, stream,
                       ks, tw, S, alpha_p, beta_p, wcut, cmax, rmax, bar, out);
}

// Round 11
// 89.105 us; speedup vs baseline: 2.2425x; 2.2425x over previous
//
#include <hip/hip_runtime.h>
#include <math.h>

#define NSIG 1000
#define NP   3997      // interp points = FFT length (odd)
#define KHALF 1999     // distinct spectrum bins: k = 0..1998 (rest mirror)
#define NW   995       // n_windows
#define WIN  20
#define STEPW 4
#define BATCH 4
#define NCH  125       // window chunks per batch row (8 windows each)
#define CW   8         // windows per chunk
#define OUTN4 3977015  // BATCH*NW*NP / 4 (exact)
#define NZBLK 500      // zero-fill blocks in dispatch 1

// ws layout (bytes):
//   ks   : [0, 65536)        BATCH*NP floats; pad is read-only garbage
//   tw   : [65536, 97512)    NP float2
//   S    : [98304, 226208)   BATCH*NP float2 (first KHALF per row used)
//   rmax : [226304, 226320)  BATCH uint
//   cmax : [226432, 228432)  BATCH*NCH floats
//   wcut : [229376, 245296)  BATCH*NW floats

__device__ __forceinline__ double interp_at(const float* __restrict__ s, int p) {
    int i0 = p >> 2;
    int si = p & 3;
    double ss = 0.25 * (double)si;
    const double A = -0.75;
    double d0 = ss + 1.0;
    double w0 = ((A * d0 - 5.0 * A) * d0 + 8.0 * A) * d0 - 4.0 * A;
    double w1 = ((A + 2.0) * ss - (A + 3.0)) * ss * ss + 1.0;
    double d2 = 1.0 - ss;
    double w2 = ((A + 2.0) * d2 - (A + 3.0)) * d2 * d2 + 1.0;
    double d3 = 2.0 - ss;
    double w3 = ((A * d3 - 5.0 * A) * d3 + 8.0 * A) * d3 - 4.0 * A;
    int im1 = i0 - 1; if (im1 < 0) im1 = 0;
    int ip1 = i0 + 1; if (ip1 > NSIG - 1) ip1 = NSIG - 1;
    int ip2 = i0 + 2; if (ip2 > NSIG - 1) ip2 = NSIG - 1;
    return w0 * (double)s[im1] + w1 * (double)s[i0] +
           w2 * (double)s[ip1] + w3 * (double)s[ip2];
}

// K1: grid (250, BATCH). bx<125: fused init + full DFT (R9 body).
// bx>=125: coalesced float4 zero-fill of out (overlaps DFT compute).
__global__ __launch_bounds__(512) void dft_init_kernel(
        const float* __restrict__ sig, const float* __restrict__ gamma_raw,
        float* __restrict__ ks, float2* __restrict__ tw, float2* __restrict__ S,
        unsigned int* __restrict__ rmax, float* __restrict__ out) {
    __shared__ float   lks[NP];
    __shared__ double2 redd[512];
    int b = blockIdx.y;
    int bx = blockIdx.x;
    int tid = threadIdx.x;

    if (bx >= 125) {
        // zero-fill stripe: zid in [0, 500)
        int zid = b * 125 + (bx - 125);
        float4* outv = (float4*)out;
        float4 z4 = make_float4(0.f, 0.f, 0.f, 0.f);
        for (size_t v = (size_t)zid * 512 + tid; v < (size_t)OUTN4;
             v += (size_t)NZBLK * 512)
            outv[v] = z4;
        return;
    }

    const float* srow = sig + b * NSIG;
    double lmin = 1e300;
    #pragma unroll
    for (int i = 0; i < 8; ++i) {
        int p = tid + i * 512;
        if (p < NP) lmin = fmin(lmin, interp_at(srow, p));
    }
    redd[tid].x = lmin;
    __syncthreads();
    for (int s = 256; s > 0; s >>= 1) {
        if (tid < s) redd[tid].x = fmin(redd[tid].x, redd[tid + s].x);
        __syncthreads();
    }
    double m = fmin(redd[0].x, 0.0);
    double g0r = (double)gamma_raw[0], g1r = (double)gamma_raw[1];
    double mx = fmax(g0r, g1r);
    double e0 = exp(g0r - mx), e1 = exp(g1r - mx);
    double inv = 1.0 / (e0 + e1);
    double g0 = e0 * inv, g1 = e1 * inv;
    #pragma unroll
    for (int i = 0; i < 8; ++i) {
        int p = tid + i * 512;
        if (p < NP) {
            double x = interp_at(srow, p) - m;
            double poly = (x + 1.3) * (x + 1.3);
            double gauss = exp(-0.5 * (x - 0.7) * (x - 0.7));
            float v = (float)(g0 * poly + g1 * gauss);
            lks[p] = v;
            if (bx == 0) ks[b * NP + p] = v;
        }
    }
    if (b == 0 && bx < 8) {
        int mm = bx * 512 + tid;
        if (mm < NP) {
            double ang = -6.283185307179586476925286766559 * ((double)mm / (double)NP);
            double sv, cv; sincos(ang, &sv, &cv);
            tw[mm] = make_float2((float)cv, (float)sv);
        }
        if (bx == 0 && tid < BATCH) rmax[tid] = 0u;
    }
    __syncthreads();

    int kk = tid & 15, tc = tid >> 4;
    int k = bx * 16 + kk;
    double sr = 0.0, si = 0.0;
    if (k < KHALF) {
        int t0 = tc * 125;
        int t1 = t0 + 125; if (t1 > NP) t1 = NP;
        const double TWO_PI = 6.283185307179586476925286766559;
        double base = -TWO_PI / (double)NP;
        double rr, ri;
        sincos(base * (double)k, &ri, &rr);
        int m0 = (k * t0) % NP;
        double pr, pi;
        sincos(base * (double)m0, &pi, &pr);
        for (int t = t0; t < t1; ++t) {
            double kv = (double)lks[t];
            sr = fma(kv, pr, sr);
            si = fma(kv, pi, si);
            double nr = pr * rr - pi * ri;
            double ni = pr * ri + pi * rr;
            pr = nr; pi = ni;
        }
    }
    redd[tid] = make_double2(sr, si);
    __syncthreads();
    for (int s = 256; s >= 16; s >>= 1) {
        if (tid < s) {
            redd[tid].x += redd[tid + s].x;
            redd[tid].y += redd[tid + s].y;
        }
        __syncthreads();
    }
    if (tid < 16) {
        int kw = bx * 16 + tid;
        if (kw < KHALF)
            S[b * NP + kw] = make_float2((float)redd[tid].x, (float)redd[tid].y);
    }
}

__device__ __forceinline__ float wavemax(float x) {
    #pragma unroll
    for (int off = 32; off > 0; off >>= 1)
        x = fmaxf(x, __shfl_xor(x, off));
    return x;
}

// sliding step bin n: W += (cn*r20 - co) * q ; q *= r
#define SLIDE1(n, co, cn) { \
    float ax = fmaf((cn), T##n.x, -(co)); \
    float ay = (cn) * T##n.y; \
    Wx##n = fmaf(ax, Q##n.x, fmaf(-ay, Q##n.y, Wx##n)); \
    Wy##n = fmaf(ax, Q##n.y, fmaf(ay, Q##n.x, Wy##n)); \
    float tq = fmaf(Q##n.x, R##n.x, -(Q##n.y * R##n.y)); \
    Q##n.y = fmaf(Q##n.x, R##n.y, Q##n.y * R##n.x); \
    Q##n.x = tq; }

#define SLIDEJ(co, cn) SLIDE1(0, co, cn) SLIDE1(1, co, cn) SLIDE1(2, co, cn) SLIDE1(3, co, cn)

#define SLIDE4(base) { \
    { float co = kp[(base) + 0], cn = kp[(base) + 20]; SLIDEJ(co, cn) } \
    { float co = kp[(base) + 1], cn = kp[(base) + 21]; SLIDEJ(co, cn) } \
    { float co = kp[(base) + 2], cn = kp[(base) + 22]; SLIDEJ(co, cn) } \
    { float co = kp[(base) + 3], cn = kp[(base) + 23]; SLIDEJ(co, cn) } }

#define WINBODY(w) { \
    float M0 = sqrtf(fmaf(Wx0, Wx0, Wy0 * Wy0)); \
    float M1m = sqrtf(fmaf(Wx1, Wx1, Wy1 * Wy1)); \
    float M2m = sqrtf(fmaf(Wx2, Wx2, Wy2 * Wy2)); \
    float M3m = sqrtf(fmaf(Wx3, Wx3, Wy3 * Wy3)); \
    float lm = fmaxf(fmaxf(M0, M1m), fmaxf(M2m, v3 ? M3m : 0.f)); \
    lm = wavemax(lm); \
    if ((tid & 63) == 0) wred[tid >> 6] = lm; \
    __syncthreads(); \
    float bm = fmaxf(fmaxf(fmaxf(wred[0], wred[1]), fmaxf(wred[2], wred[3])), \
                     fmaxf(fmaxf(wred[4], wred[5]), fmaxf(wred[6], wred[7]))); \
    float cut = bm * alpha; \
    __syncthreads(); \
    if (w0 + (w) < NW) { \
        if (tid == 0) wcut[b * NW + w0 + (w)] = cut; \
        float r0v = 0.f, r1v = 0.f, r2v = 0.f, r3v = 0.f; \
        { float dr = Sv0.x - Wx0, di = Sv0.y - Wy0; float m1 = sqrtf(fmaf(dr, dr, di * di)); \
          if (M0 > cut) r0v = fminf(M0, m1 * M0); } \
        { float dr = Sv1.x - Wx1, di = Sv1.y - Wy1; float m1 = sqrtf(fmaf(dr, dr, di * di)); \
          if (M1m > cut) r1v = fminf(M1m, m1 * M1m); } \
        { float dr = Sv2.x - Wx2, di = Sv2.y - Wy2; float m1 = sqrtf(fmaf(dr, dr, di * di)); \
          if (M2m > cut) r2v = fminf(M2m, m1 * M2m); } \
        { float dr = Sv3.x - Wx3, di = Sv3.y - Wy3; float m1 = sqrtf(fmaf(dr, dr, di * di)); \
          if (M3m > cut) r3v = fminf(M3m, m1 * M3m); } \
        rl = fmaxf(rl, fmaxf(fmaxf(r0v, r1v), fmaxf(r2v, r3v))); \
    } }

// K2: chunk of 8 windows; sliding spectrum; only wcut/cmax/rmax stores.
__global__ __launch_bounds__(512, 4) void window_kernel(
        const float* __restrict__ ks, const float2* __restrict__ tw,
        const float2* __restrict__ S, const float* __restrict__ alpha_p,
        float* __restrict__ wcut, float* __restrict__ cmax,
        unsigned int* __restrict__ rmax) {
    __shared__ float wred[8];
    int b = blockIdx.y;
    int wc = blockIdx.x;
    int w0 = wc * CW;
    int s0 = w0 * STEPW;
    int tid = threadIdx.x;
    float alpha = *alpha_p;
    const float* kp = ks + b * NP + s0;   // block-uniform -> s_load taps

    int k0 = tid, k1 = tid + 512, k2 = tid + 1024, k3 = tid + 1536;
    bool v3 = (k3 < KHALF);

    float2 R0 = tw[k0], R1 = tw[k1], R2 = tw[k2], R3 = tw[k3];
    float2 T0 = tw[(20 * k0) % NP], T1 = tw[(20 * k1) % NP],
           T2 = tw[(20 * k2) % NP], T3 = tw[(20 * k3) % NP];
    float2 Q0 = tw[(k0 * s0) % NP], Q1 = tw[(k1 * s0) % NP],
           Q2 = tw[(k2 * s0) % NP], Q3 = tw[(k3 * s0) % NP];
    const float2* Sb = S + b * NP;
    float2 Sv0 = Sb[k0], Sv1 = Sb[k1], Sv2 = Sb[k2], Sv3 = Sb[k3];

    float Dx0 = kp[19], Dy0 = 0.f, Dx1 = kp[19], Dy1 = 0.f,
          Dx2 = kp[19], Dy2 = 0.f, Dx3 = kp[19], Dy3 = 0.f;
    #pragma unroll
    for (int j = 18; j >= 0; --j) {
        float a = kp[j];
        float nx, ny;
        nx = fmaf(Dx0, R0.x, fmaf(-Dy0, R0.y, a));
        ny = fmaf(Dy0, R0.x, Dx0 * R0.y);
        Dx0 = nx; Dy0 = ny;
        nx = fmaf(Dx1, R1.x, fmaf(-Dy1, R1.y, a));
        ny = fmaf(Dy1, R1.x, Dx1 * R1.y);
        Dx1 = nx; Dy1 = ny;
        nx = fmaf(Dx2, R2.x, fmaf(-Dy2, R2.y, a));
        ny = fmaf(Dy2, R2.x, Dx2 * R2.y);
        Dx2 = nx; Dy2 = ny;
        nx = fmaf(Dx3, R3.x, fmaf(-Dy3, R3.y, a));
        ny = fmaf(Dy3, R3.x, Dx3 * R3.y);
        Dx3 = nx; Dy3 = ny;
    }
    float Wx0 = fmaf(Q0.x, Dx0, -(Q0.y * Dy0));
    float Wy0 = fmaf(Q0.x, Dy0, Q0.y * Dx0);
    float Wx1 = fmaf(Q1.x, Dx1, -(Q1.y * Dy1));
    float Wy1 = fmaf(Q1.x, Dy1, Q1.y * Dx1);
    float Wx2 = fmaf(Q2.x, Dx2, -(Q2.y * Dy2));
    float Wy2 = fmaf(Q2.x, Dy2, Q2.y * Dx2);
    float Wx3 = fmaf(Q3.x, Dx3, -(Q3.y * Dy3));
    float Wy3 = fmaf(Q3.x, Dy3, Q3.y * Dx3);

    float rl = 0.f;

    WINBODY(0)
    SLIDE4(0)  WINBODY(1)
    SLIDE4(4)  WINBODY(2)
    SLIDE4(8)  WINBODY(3)
    SLIDE4(12) WINBODY(4)
    SLIDE4(16) WINBODY(5)
    SLIDE4(20) WINBODY(6)
    SLIDE4(24) WINBODY(7)

    rl = wavemax(rl);
    if ((tid & 63) == 0) wred[tid >> 6] = rl;
    __syncthreads();
    if (tid == 0) {
        float bm = fmaxf(fmaxf(fmaxf(wred[0], wred[1]), fmaxf(wred[2], wred[3])),
                         fmaxf(fmaxf(wred[4], wred[5]), fmaxf(wred[6], wred[7])));
        cmax[b * NCH + wc] = bm;
        atomicMax(&rmax[b], __float_as_uint(bm));
    }
}

// survivor bin epilogue (out already zeroed; write values incl. explicit 0s)
#define FINBIN(n, kn, valid) { \
    if (valid) { \
        float M = sqrtf(fmaf(Dx##n, Dx##n, Dy##n * Dy##n)); \
        float2 P = tw[((kn) * start) % NP]; \
        float Wr = fmaf(P.x, Dx##n, -(P.y * Dy##n)); \
        float Wi = fmaf(P.x, Dy##n, P.y * Dx##n); \
        float2 Sv = Sb[kn]; \
        float dr = Sv.x - Wr, di = Sv.y - Wi; \
        float M1 = sqrtf(fmaf(dr, dr, di * di)); \
        float res = 0.f; \
        if (M > cut) res = fminf(M, M1 * M); \
        float f = (res > thr) ? res : 0.f; \
        out[base + (kn)] = f; \
        if ((kn) > 0) out[base + NP - (kn)] = f; \
    } }

// K3: sparse finalize. One block per chunk; dead chunks return immediately
// (out rows already zeroed by K1). Surviving chunks recompute their 8 rows
// by Horner and write full mirrored rows.
__global__ __launch_bounds__(512) void sparse_kernel(
        const float* __restrict__ ks, const float2* __restrict__ tw,
        const float2* __restrict__ S, const float* __restrict__ wcut,
        const float* __restrict__ cmax, const unsigned int* __restrict__ rmax,
        const float* __restrict__ beta_p, float* __restrict__ out) {
    int b = blockIdx.y, wc = blockIdx.x;
    float thr = (*beta_p) * __uint_as_float(rmax[b]);
    if (cmax[b * NCH + wc] <= thr) return;

    int tid = threadIdx.x;
    int k0 = tid, k1 = tid + 512, k2 = tid + 1024, k3 = tid + 1536;
    bool v3 = (k3 < KHALF);
    float2 R0 = tw[k0], R1 = tw[k1], R2 = tw[k2], R3 = tw[k3];
    const float2* Sb = S + b * NP;

    for (int i = 0; i < CW; ++i) {
        int w = wc * CW + i;
        if (w >= NW) break;
        int start = w * STEPW;
        const float* kp = ks + b * NP + start;
        float cut = wcut[b * NW + w];
        size_t base = (size_t)(b * NW + w) * NP;
        float Dx0 = kp[19], Dy0 = 0.f, Dx1 = kp[19], Dy1 = 0.f,
              Dx2 = kp[19], Dy2 = 0.f, Dx3 = kp[19], Dy3 = 0.f;
        #pragma unroll
        for (int j = 18; j >= 0; --j) {
            float a = kp[j];
            float nx, ny;
            nx = fmaf(Dx0, R0.x, fmaf(-Dy0, R0.y, a));
            ny = fmaf(Dy0, R0.x, Dx0 * R0.y);
            Dx0 = nx; Dy0 = ny;
            nx = fmaf(Dx1, R1.x, fmaf(-Dy1, R1.y, a));
            ny = fmaf(Dy1, R1.x, Dx1 * R1.y);
            Dx1 = nx; Dy1 = ny;
            nx = fmaf(Dx2, R2.x, fmaf(-Dy2, R2.y, a));
            ny = fmaf(Dy2, R2.x, Dx2 * R2.y);
            Dx2 = nx; Dy2 = ny;
            nx = fmaf(Dx3, R3.x, fmaf(-Dy3, R3.y, a));
            ny = fmaf(Dy3, R3.x, Dx3 * R3.y);
            Dx3 = nx; Dy3 = ny;
        }
        FINBIN(0, k0, true)
        FINBIN(1, k1, true)
        FINBIN(2, k2, true)
        FINBIN(3, k3, v3)
    }
}

extern "C" void kernel_launch(void* const* d_in, const int* in_sizes, int n_in,
                              void* d_out, int out_size, void* d_ws, size_t ws_size,
                              hipStream_t stream) {
    const float* sig       = (const float*)d_in[0];
    const float* alpha_p   = (const float*)d_in[1];
    const float* beta_p    = (const float*)d_in[2];
    const float* gamma_raw = (const float*)d_in[3];
    char* ws = (char*)d_ws;
    float*        ks   = (float*)(ws + 0);
    float2*       tw   = (float2*)(ws + 65536);
    float2*       S    = (float2*)(ws + 98304);
    unsigned int* rmax = (unsigned int*)(ws + 226304);
    float*        cmax = (float*)(ws + 226432);
    float*        wcut = (float*)(ws + 229376);
    float* out = (float*)d_out;

    hipLaunchKernelGGL(dft_init_kernel, dim3(250, BATCH), dim3(512), 0, stream,
                       sig, gamma_raw, ks, tw, S, rmax, out);
    hipLaunchKernelGGL(window_kernel,   dim3(NCH, BATCH), dim3(512), 0, stream,
                       ks, tw, S, alpha_p, wcut, cmax, rmax);
    hipLaunchKernelGGL(sparse_kernel,   dim3(NCH, BATCH), dim3(512), 0, stream,
                       ks, tw, S, wcut, cmax, rmax, beta_p, out);
}

// Round 12
// 60.882 us; speedup vs baseline: 3.2821x; 1.4636x over previous
//
#include <hip/hip_runtime.h>
#include <math.h>

#define NSIG 1000
#define NP   3997      // interp points = FFT length (odd)
#define KHALF 1999     // distinct spectrum bins: k = 0..1998 (rest mirror)
#define NW   995       // n_windows
#define WIN  20
#define STEPW 4
#define BATCH 4
#define NCH  125       // window chunks per batch row (8 windows each)
#define CW   8         // windows per chunk

// ws layout (bytes):
//   ks   : [0, 65536)        BATCH*NP floats; pad is read-only garbage
//   tw   : [65536, 97512)    NP float2
//   S    : [98304, 226208)   BATCH*NP float2 (first KHALF per row used)
//   rmax : [226304, 226320)  BATCH uint
//   cmax : [226432, 228432)  BATCH*NCH floats
//   wcut : [229376, 245296)  BATCH*NW floats

__device__ __forceinline__ double interp_at(const float* __restrict__ s, int p) {
    int i0 = p >> 2;
    int si = p & 3;
    double ss = 0.25 * (double)si;
    const double A = -0.75;
    double d0 = ss + 1.0;
    double w0 = ((A * d0 - 5.0 * A) * d0 + 8.0 * A) * d0 - 4.0 * A;
    double w1 = ((A + 2.0) * ss - (A + 3.0)) * ss * ss + 1.0;
    double d2 = 1.0 - ss;
    double w2 = ((A + 2.0) * d2 - (A + 3.0)) * d2 * d2 + 1.0;
    double d3 = 2.0 - ss;
    double w3 = ((A * d3 - 5.0 * A) * d3 + 8.0 * A) * d3 - 4.0 * A;
    int im1 = i0 - 1; if (im1 < 0) im1 = 0;
    int ip1 = i0 + 1; if (ip1 > NSIG - 1) ip1 = NSIG - 1;
    int ip2 = i0 + 2; if (ip2 > NSIG - 1) ip2 = NSIG - 1;
    return w0 * (double)s[im1] + w1 * (double)s[i0] +
           w2 * (double)s[ip1] + w3 * (double)s[ip2];
}

// K1: fused init + full DFT (identical to R9).
__global__ __launch_bounds__(512) void dft_init_kernel(
        const float* __restrict__ sig, const float* __restrict__ gamma_raw,
        float* __restrict__ ks, float2* __restrict__ tw, float2* __restrict__ S,
        unsigned int* __restrict__ rmax) {
    __shared__ float   lks[NP];
    __shared__ double2 redd[512];
    int b = blockIdx.y;
    int bx = blockIdx.x;
    int tid = threadIdx.x;
    const float* srow = sig + b * NSIG;

    double lmin = 1e300;
    #pragma unroll
    for (int i = 0; i < 8; ++i) {
        int p = tid + i * 512;
        if (p < NP) lmin = fmin(lmin, interp_at(srow, p));
    }
    redd[tid].x = lmin;
    __syncthreads();
    for (int s = 256; s > 0; s >>= 1) {
        if (tid < s) redd[tid].x = fmin(redd[tid].x, redd[tid + s].x);
        __syncthreads();
    }
    double m = fmin(redd[0].x, 0.0);
    double g0r = (double)gamma_raw[0], g1r = (double)gamma_raw[1];
    double mx = fmax(g0r, g1r);
    double e0 = exp(g0r - mx), e1 = exp(g1r - mx);
    double inv = 1.0 / (e0 + e1);
    double g0 = e0 * inv, g1 = e1 * inv;
    #pragma unroll
    for (int i = 0; i < 8; ++i) {
        int p = tid + i * 512;
        if (p < NP) {
            double x = interp_at(srow, p) - m;
            double poly = (x + 1.3) * (x + 1.3);
            double gauss = exp(-0.5 * (x - 0.7) * (x - 0.7));
            float v = (float)(g0 * poly + g1 * gauss);
            lks[p] = v;
            if (bx == 0) ks[b * NP + p] = v;
        }
    }
    if (b == 0 && bx < 8) {
        int mm = bx * 512 + tid;
        if (mm < NP) {
            double ang = -6.283185307179586476925286766559 * ((double)mm / (double)NP);
            double sv, cv; sincos(ang, &sv, &cv);
            tw[mm] = make_float2((float)cv, (float)sv);
        }
        if (bx == 0 && tid < BATCH) rmax[tid] = 0u;
    }
    __syncthreads();

    int kk = tid & 15, tc = tid >> 4;
    int k = bx * 16 + kk;
    double sr = 0.0, si = 0.0;
    if (k < KHALF) {
        int t0 = tc * 125;
        int t1 = t0 + 125; if (t1 > NP) t1 = NP;
        const double TWO_PI = 6.283185307179586476925286766559;
        double base = -TWO_PI / (double)NP;
        double rr, ri;
        sincos(base * (double)k, &ri, &rr);
        int m0 = (k * t0) % NP;
        double pr, pi;
        sincos(base * (double)m0, &pi, &pr);
        for (int t = t0; t < t1; ++t) {
            double kv = (double)lks[t];
            sr = fma(kv, pr, sr);
            si = fma(kv, pi, si);
            double nr = pr * rr - pi * ri;
            double ni = pr * ri + pi * rr;
            pr = nr; pi = ni;
        }
    }
    redd[tid] = make_double2(sr, si);
    __syncthreads();
    for (int s = 256; s >= 16; s >>= 1) {
        if (tid < s) {
            redd[tid].x += redd[tid + s].x;
            redd[tid].y += redd[tid + s].y;
        }
        __syncthreads();
    }
    if (tid < 16) {
        int kw = bx * 16 + tid;
        if (kw < KHALF)
            S[b * NP + kw] = make_float2((float)redd[tid].x, (float)redd[tid].y);
    }
}

__device__ __forceinline__ float wavemax(float x) {
    #pragma unroll
    for (int off = 32; off > 0; off >>= 1)
        x = fmaxf(x, __shfl_xor(x, off));
    return x;
}

// sliding step bin n: W += (cn*r20 - co) * q ; q *= r
#define SLIDE1(n, co, cn) { \
    float ax = fmaf((cn), T##n.x, -(co)); \
    float ay = (cn) * T##n.y; \
    Wx##n = fmaf(ax, Q##n.x, fmaf(-ay, Q##n.y, Wx##n)); \
    Wy##n = fmaf(ax, Q##n.y, fmaf(ay, Q##n.x, Wy##n)); \
    float tq = fmaf(Q##n.x, R##n.x, -(Q##n.y * R##n.y)); \
    Q##n.y = fmaf(Q##n.x, R##n.y, Q##n.y * R##n.x); \
    Q##n.x = tq; }

#define SLIDEJ(co, cn) SLIDE1(0, co, cn) SLIDE1(1, co, cn) SLIDE1(2, co, cn) SLIDE1(3, co, cn)

#define SLIDE4(base) { \
    { float co = kp[(base) + 0], cn = kp[(base) + 20]; SLIDEJ(co, cn) } \
    { float co = kp[(base) + 1], cn = kp[(base) + 21]; SLIDEJ(co, cn) } \
    { float co = kp[(base) + 2], cn = kp[(base) + 22]; SLIDEJ(co, cn) } \
    { float co = kp[(base) + 3], cn = kp[(base) + 23]; SLIDEJ(co, cn) } }

#define WINBODY(w) { \
    float M0 = sqrtf(fmaf(Wx0, Wx0, Wy0 * Wy0)); \
    float M1m = sqrtf(fmaf(Wx1, Wx1, Wy1 * Wy1)); \
    float M2m = sqrtf(fmaf(Wx2, Wx2, Wy2 * Wy2)); \
    float M3m = sqrtf(fmaf(Wx3, Wx3, Wy3 * Wy3)); \
    float lm = fmaxf(fmaxf(M0, M1m), fmaxf(M2m, v3 ? M3m : 0.f)); \
    lm = wavemax(lm); \
    if ((tid & 63) == 0) wred[tid >> 6] = lm; \
    __syncthreads(); \
    float bm = fmaxf(fmaxf(fmaxf(wred[0], wred[1]), fmaxf(wred[2], wred[3])), \
                     fmaxf(fmaxf(wred[4], wred[5]), fmaxf(wred[6], wred[7]))); \
    float cut = bm * alpha; \
    __syncthreads(); \
    if (w0 + (w) < NW) { \
        if (tid == 0) wcut[b * NW + w0 + (w)] = cut; \
        float r0v = 0.f, r1v = 0.f, r2v = 0.f, r3v = 0.f; \
        { float dr = Sv0.x - Wx0, di = Sv0.y - Wy0; float m1 = sqrtf(fmaf(dr, dr, di * di)); \
          if (M0 > cut) r0v = fminf(M0, m1 * M0); } \
        { float dr = Sv1.x - Wx1, di = Sv1.y - Wy1; float m1 = sqrtf(fmaf(dr, dr, di * di)); \
          if (M1m > cut) r1v = fminf(M1m, m1 * M1m); } \
        { float dr = Sv2.x - Wx2, di = Sv2.y - Wy2; float m1 = sqrtf(fmaf(dr, dr, di * di)); \
          if (M2m > cut) r2v = fminf(M2m, m1 * M2m); } \
        { float dr = Sv3.x - Wx3, di = Sv3.y - Wy3; float m1 = sqrtf(fmaf(dr, dr, di * di)); \
          if (M3m > cut) r3v = fminf(M3m, m1 * M3m); } \
        rl = fmaxf(rl, fmaxf(fmaxf(r0v, r1v), fmaxf(r2v, r3v))); \
    } }

// K2: chunk of 8 windows; sliding spectrum; only wcut/cmax/rmax stores (R9).
__global__ __launch_bounds__(512, 4) void window_kernel(
        const float* __restrict__ ks, const float2* __restrict__ tw,
        const float2* __restrict__ S, const float* __restrict__ alpha_p,
        float* __restrict__ wcut, float* __restrict__ cmax,
        unsigned int* __restrict__ rmax) {
    __shared__ float wred[8];
    int b = blockIdx.y;
    int wc = blockIdx.x;
    int w0 = wc * CW;
    int s0 = w0 * STEPW;
    int tid = threadIdx.x;
    float alpha = *alpha_p;
    const float* kp = ks + b * NP + s0;   // block-uniform -> s_load taps

    int k0 = tid, k1 = tid + 512, k2 = tid + 1024, k3 = tid + 1536;
    bool v3 = (k3 < KHALF);

    float2 R0 = tw[k0], R1 = tw[k1], R2 = tw[k2], R3 = tw[k3];
    float2 T0 = tw[(20 * k0) % NP], T1 = tw[(20 * k1) % NP],
           T2 = tw[(20 * k2) % NP], T3 = tw[(20 * k3) % NP];
    float2 Q0 = tw[(k0 * s0) % NP], Q1 = tw[(k1 * s0) % NP],
           Q2 = tw[(k2 * s0) % NP], Q3 = tw[(k3 * s0) % NP];
    const float2* Sb = S + b * NP;
    float2 Sv0 = Sb[k0], Sv1 = Sb[k1], Sv2 = Sb[k2], Sv3 = Sb[k3];

    float Dx0 = kp[19], Dy0 = 0.f, Dx1 = kp[19], Dy1 = 0.f,
          Dx2 = kp[19], Dy2 = 0.f, Dx3 = kp[19], Dy3 = 0.f;
    #pragma unroll
    for (int j = 18; j >= 0; --j) {
        float a = kp[j];
        float nx, ny;
        nx = fmaf(Dx0, R0.x, fmaf(-Dy0, R0.y, a));
        ny = fmaf(Dy0, R0.x, Dx0 * R0.y);
        Dx0 = nx; Dy0 = ny;
        nx = fmaf(Dx1, R1.x, fmaf(-Dy1, R1.y, a));
        ny = fmaf(Dy1, R1.x, Dx1 * R1.y);
        Dx1 = nx; Dy1 = ny;
        nx = fmaf(Dx2, R2.x, fmaf(-Dy2, R2.y, a));
        ny = fmaf(Dy2, R2.x, Dx2 * R2.y);
        Dx2 = nx; Dy2 = ny;
        nx = fmaf(Dx3, R3.x, fmaf(-Dy3, R3.y, a));
        ny = fmaf(Dy3, R3.x, Dx3 * R3.y);
        Dx3 = nx; Dy3 = ny;
    }
    float Wx0 = fmaf(Q0.x, Dx0, -(Q0.y * Dy0));
    float Wy0 = fmaf(Q0.x, Dy0, Q0.y * Dx0);
    float Wx1 = fmaf(Q1.x, Dx1, -(Q1.y * Dy1));
    float Wy1 = fmaf(Q1.x, Dy1, Q1.y * Dx1);
    float Wx2 = fmaf(Q2.x, Dx2, -(Q2.y * Dy2));
    float Wy2 = fmaf(Q2.x, Dy2, Q2.y * Dx2);
    float Wx3 = fmaf(Q3.x, Dx3, -(Q3.y * Dy3));
    float Wy3 = fmaf(Q3.x, Dy3, Q3.y * Dx3);

    float rl = 0.f;

    WINBODY(0)
    SLIDE4(0)  WINBODY(1)
    SLIDE4(4)  WINBODY(2)
    SLIDE4(8)  WINBODY(3)
    SLIDE4(12) WINBODY(4)
    SLIDE4(16) WINBODY(5)
    SLIDE4(20) WINBODY(6)
    SLIDE4(24) WINBODY(7)

    rl = wavemax(rl);
    if ((tid & 63) == 0) wred[tid >> 6] = rl;
    __syncthreads();
    if (tid == 0) {
        float bm = fmaxf(fmaxf(fmaxf(wred[0], wred[1]), fmaxf(wred[2], wred[3])),
                         fmaxf(fmaxf(wred[4], wred[5]), fmaxf(wred[6], wred[7])));
        cmax[b * NCH + wc] = bm;
        atomicMax(&rmax[b], __float_as_uint(bm));
    }
}

// finalize survivor bin epilogue
#define FINBIN(n, kn, valid) { \
    if (valid) { \
        float M = sqrtf(fmaf(Dx##n, Dx##n, Dy##n * Dy##n)); \
        float2 P = tw[((kn) * start) % NP]; \
        float Wr = fmaf(P.x, Dx##n, -(P.y * Dy##n)); \
        float Wi = fmaf(P.x, Dy##n, P.y * Dx##n); \
        float2 Sv = Sb[kn]; \
        float dr = Sv.x - Wr, di = Sv.y - Wi; \
        float M1 = sqrtf(fmaf(dr, dr, di * di)); \
        float res = 0.f; \
        if (M > cut) res = fminf(M, M1 * M); \
        float f = (res > thr) ? res : 0.f; \
        out[base + (kn)] = f; \
        if ((kn) > 0) out[base + NP - (kn)] = f; \
    } }

// K3: one block per (b,w) row (R9 structure). Dead chunks -> dense zero row,
// now float4-vectorized (16B/lane). Survivors -> Horner recompute + mirrored
// write (unchanged from R9).
__global__ __launch_bounds__(512) void finalize_kernel(
        const float* __restrict__ ks, const float2* __restrict__ tw,
        const float2* __restrict__ S, const float* __restrict__ wcut,
        const float* __restrict__ cmax, const unsigned int* __restrict__ rmax,
        const float* __restrict__ beta_p, float* __restrict__ out) {
    int b = blockIdx.y, w = blockIdx.x;
    int tid = threadIdx.x;
    float thr = (*beta_p) * __uint_as_float(rmax[b]);
    size_t base = (size_t)(b * NW + w) * NP;
    if (cmax[b * NCH + (w >> 3)] <= thr) {
        // vectorized dense zero row: head scalars to 16B alignment, float4
        // body, tail scalars
        int h = ((4 - (int)(base & 3)) & 3);
        int nv = (NP - h) >> 2;            // float4 count (998 or 999)
        int t0 = h + (nv << 2);
        float4* vp = (float4*)(out + base + h);
        float4 z4 = make_float4(0.f, 0.f, 0.f, 0.f);
        for (int v = tid; v < nv; v += 512) vp[v] = z4;
        if (tid < h) out[base + tid] = 0.f;
        if (tid < NP - t0) out[base + t0 + tid] = 0.f;
        return;
    }
    int start = w * STEPW;
    const float* kp = ks + b * NP + start;
    float cut = wcut[b * NW + w];
    const float2* Sb = S + b * NP;
    int k0 = tid, k1 = tid + 512, k2 = tid + 1024, k3 = tid + 1536;
    bool v3 = (k3 < KHALF);
    float2 R0 = tw[k0], R1 = tw[k1], R2 = tw[k2], R3 = tw[k3];
    float Dx0 = kp[19], Dy0 = 0.f, Dx1 = kp[19], Dy1 = 0.f,
          Dx2 = kp[19], Dy2 = 0.f, Dx3 = kp[19], Dy3 = 0.f;
    #pragma unroll
    for (int j = 18; j >= 0; --j) {
        float a = kp[j];
        float nx, ny;
        nx = fmaf(Dx0, R0.x, fmaf(-Dy0, R0.y, a));
        ny = fmaf(Dy0, R0.x, Dx0 * R0.y);
        Dx0 = nx; Dy0 = ny;
        nx = fmaf(Dx1, R1.x, fmaf(-Dy1, R1.y, a));
        ny = fmaf(Dy1, R1.x, Dx1 * R1.y);
        Dx1 = nx; Dy1 = ny;
        nx = fmaf(Dx2, R2.x, fmaf(-Dy2, R2.y, a));
        ny = fmaf(Dy2, R2.x, Dx2 * R2.y);
        Dx2 = nx; Dy2 = ny;
        nx = fmaf(Dx3, R3.x, fmaf(-Dy3, R3.y, a));
        ny = fmaf(Dy3, R3.x, Dx3 * R3.y);
        Dx3 = nx; Dy3 = ny;
    }
    FINBIN(0, k0, true)
    FINBIN(1, k1, true)
    FINBIN(2, k2, true)
    FINBIN(3, k3, v3)
}

extern "C" void kernel_launch(void* const* d_in, const int* in_sizes, int n_in,
                              void* d_out, int out_size, void* d_ws, size_t ws_size,
                              hipStream_t stream) {
    const float* sig       = (const float*)d_in[0];
    const float* alpha_p   = (const float*)d_in[1];
    const float* beta_p    = (const float*)d_in[2];
    const float* gamma_raw = (const float*)d_in[3];
    char* ws = (char*)d_ws;
    float*        ks   = (float*)(ws + 0);
    float2*       tw   = (float2*)(ws + 65536);
    float2*       S    = (float2*)(ws + 98304);
    unsigned int* rmax = (unsigned int*)(ws + 226304);
    float*        cmax = (float*)(ws + 226432);
    float*        wcut = (float*)(ws + 229376);
    float* out = (float*)d_out;

    hipLaunchKernelGGL(dft_init_kernel, dim3(125, BATCH), dim3(512), 0, stream,
                       sig, gamma_raw, ks, tw, S, rmax);
    hipLaunchKernelGGL(window_kernel,   dim3(NCH, BATCH), dim3(512), 0, stream,
                       ks, tw, S, alpha_p, wcut, cmax, rmax);
    hipLaunchKernelGGL(finalize_kernel, dim3(NW, BATCH),  dim3(512), 0, stream,
                       ks, tw, S, wcut, cmax, rmax, beta_p, out);
}